// Round 5
// baseline (132.932 us; speedup 1.0000x reference)
//
#include <hip/hip_runtime.h>

// HistoLoss: B=1024, T=256, C=16, NB=64; TC=4096; x flat = [b][tc]
//
// R18: DIAGNOSTIC ROUND (intentional dur regression). Evidence so far:
//   R15 (1.5x fewer inner inst): flat. R17 (2x blocks, pipelined): -0.7us.
//   R16: k1 ~17-18us. => k1 is NOT VALU-issue-bound; stalled on something
//   unobserved (k1 never appears in rocprof top-5 -- hidden under 43us
//   poison fills). This round repeats k1's COMPUTE PHASE x4 in-kernel
//   (stage once; compute+store x4, identical bytes each rep -> absmax 0.0)
//   so k1 becomes the top dispatch and we finally read its VALUBusy /
//   Occupancy / LDS_BANK_CONFLICT. LDS base laundered per rep (rule #17)
//   to defeat cross-rep CSE.
//   dur ~= 89.6 + 3C. Branches: VALUBusy>80% -> issue-bound (throttle or
//   accounting wrong); <60% -> latency-bound -> ILP/occupancy fix.
//
// k1 structure (= R17 best, 89.62us): 256 thr = 16 c x 16 kq; block =
//   (t, 64-b chunk), grid 4096. LDS xsp[c][36] u32 u16-pair fixed-point
//   (x*4096; bit-exact: |xq-qlo| <= ~35K < 65536-qw). Inner: 4 VOP3P per
//   2 indicators. k2 unchanged.

#define T_DIM   256
#define C_DIM   16
#define NB      64
#define TC      4096
#define CHUNKS  16
#define BBLK    64
#define KPT     4
#define PITCH   36             // xsp row pitch in u32 (32 pairs + 4 pad)
#define QSCALE  4096.0f
#define REPS    4              // diagnostic compute-phase repeats

__global__ __launch_bounds__(256, 8) void histo_count_kernel(
    const float* __restrict__ x,       // [1024, 4096]
    const float* __restrict__ locs,    // [4096, 64]
    const float* __restrict__ deltas,  // [4096]
    unsigned char* __restrict__ counts,// [CHUNKS][4096][64] u8
    float* __restrict__ out)           // [1] (zeroed for k2's atomics)
{
    __shared__ int xsp[C_DIM * PITCH];           // 16 x 36 u32 = 2304 B
    const int tid   = threadIdx.x;
    const int t     = blockIdx.x & 255;
    const int chunk = blockIdx.x >> 8;           // 0..15 (64 b each)

    if (blockIdx.x == 0 && tid == 0) out[0] = 0.0f;

    // Stage x[chunk*64 .. +63][t*16 .. +15] -> u16-pair fixed-point.
    if (tid < 128) {
        const int bpair = tid >> 2;              // 0..31
        const int c4    = (tid & 3) * 4;
        const int b0    = 2 * bpair;
        const float* r0 = x + (size_t)(chunk * BBLK + b0) * TC + t * C_DIM + c4;
        const float4 va = *(const float4*)r0;
        const float4 vb = *(const float4*)(r0 + TC);
        const float a[4] = {va.x, va.y, va.z, va.w};
        const float b[4] = {vb.x, vb.y, vb.z, vb.w};
#pragma unroll
        for (int k = 0; k < 4; ++k) {
            const int pa = __float2int_rn(a[k] * QSCALE);
            const int pb = __float2int_rn(b[k] * QSCALE);
            xsp[(c4 + k) * PITCH + bpair] = (pa & 0xFFFF) | (pb << 16);
        }
    }

    const int kq = tid & 15;           // bins [kq*4, kq*4+4)
    const int c  = tid >> 4;           // 0..15
    const int tc = t * C_DIM + c;

    const float hf = 0.5f * deltas[tc];
    const int   qw = __float2int_rn(2.0f * hf * QSCALE);
    const int   w2 = (qw & 0xFFFF) | (qw << 16);
    const int  one2 = 0x00010001;

    int lo2[KPT];
    const float4 lv = *(const float4*)(locs + (size_t)tc * NB + kq * KPT);
    const float lf[4] = {lv.x, lv.y, lv.z, lv.w};
#pragma unroll
    for (int j = 0; j < KPT; ++j) {
        const int q = __float2int_rn((lf[j] - hf) * QSCALE);
        lo2[j] = (q & 0xFFFF) | (q << 16);
    }

    __syncthreads();

    const int4* xr = (const int4*)(xsp + c * PITCH);
    unsigned* dst = (unsigned*)(counts + (size_t)chunk * (TC * NB)
                                       + (size_t)tc * NB + kq * KPT);

    for (int rep = 0; rep < REPS; ++rep) {
        // Launder the LDS offset so each rep re-reads LDS and recomputes
        // (defeats cross-rep CSE; off is always 0).
        unsigned off = 0;
        asm volatile("" : "+v"(off));
        const int4* xp = xr + off;

        int acc[KPT];
#pragma unroll
        for (int j = 0; j < KPT; ++j) acc[j] = 0;

#pragma unroll 4
        for (int g = 0; g < 8; ++g) {
            const int4 u = xp[g];
            const int xx[4] = {u.x, u.y, u.z, u.w};
#pragma unroll
            for (int q = 0; q < 4; ++q) {
#pragma unroll
                for (int j = 0; j < KPT; ++j) {
                    int tmp;
                    asm("v_pk_sub_u16 %0, %2, %3\n\t"
                        "v_pk_sub_u16 %0, %4, %0 clamp\n\t"
                        "v_pk_min_u16 %0, %0, %5\n\t"
                        "v_pk_add_u16 %1, %1, %0"
                        : "=&v"(tmp), "+v"(acc[j])
                        : "v"(xx[q]), "v"(lo2[j]), "v"(w2), "v"(one2));
                }
            }
        }

        unsigned pack = 0;
#pragma unroll
        for (int j = 0; j < KPT; ++j) {
            const unsigned s = ((unsigned)acc[j] + ((unsigned)acc[j] >> 16)) & 0xFFu;
            pack |= s << (8 * j);                          // <=64 each
        }
        *dst = pack;                   // identical bytes every rep
    }
}

__global__ __launch_bounds__(256) void histo_loss_kernel(
    const unsigned char* __restrict__ counts, // [CHUNKS][4096][64]
    const float* __restrict__ deltas,         // [4096]
    const float* __restrict__ dens,           // [4096, 64]
    float* __restrict__ out)                  // [1]
{
    const int gid = blockIdx.x * 256 + threadIdx.x;
    const int i0  = gid * 4;                  // 4 consecutive items, same tc

    int cnt[4] = {0, 0, 0, 0};
#pragma unroll
    for (int ch = 0; ch < CHUNKS; ++ch) {
        const unsigned u = *(const unsigned*)(counts + (size_t)ch * (TC * NB) + i0);
#pragma unroll
        for (int q = 0; q < 4; ++q)
            cnt[q] += (int)((u >> (8 * q)) & 0xffu);
    }

    const float delta = deltas[i0 >> 6];
    const float4 dv = *(const float4*)(dens + i0);
    float s = fabsf((cnt[0] * (1.0f / 1024.0f)) / delta - dv.x)
            + fabsf((cnt[1] * (1.0f / 1024.0f)) / delta - dv.y)
            + fabsf((cnt[2] * (1.0f / 1024.0f)) / delta - dv.z)
            + fabsf((cnt[3] * (1.0f / 1024.0f)) / delta - dv.w);

#pragma unroll
    for (int off = 32; off > 0; off >>= 1)
        s += __shfl_down(s, off, 64);

    __shared__ float sb[4];
    if ((threadIdx.x & 63) == 0) sb[threadIdx.x >> 6] = s;
    __syncthreads();

    if (threadIdx.x == 0)   // REG * mean over (t,c,k) = sum / 262144
        atomicAdd(out, (sb[0] + sb[1] + sb[2] + sb[3]) * (1.0f / 262144.0f));
}

extern "C" void kernel_launch(void* const* d_in, const int* in_sizes, int n_in,
                              void* d_out, int out_size, void* d_ws, size_t ws_size,
                              hipStream_t stream) {
    const float* x      = (const float*)d_in[0];  // x_fake    [1024,256,16]
    const float* locs   = (const float*)d_in[1];  // locs      [256,16,64]
    const float* deltas = (const float*)d_in[2];  // deltas    [256,16]
    const float* dens   = (const float*)d_in[3];  // densities [256,16,64]
    float* out = (float*)d_out;
    unsigned char* cnts = (unsigned char*)d_ws;   // 4 MB scratch

    histo_count_kernel<<<T_DIM * CHUNKS, 256, 0, stream>>>(x, locs, deltas, cnts, out);
    histo_loss_kernel<<<(TC * NB) / (256 * 4), 256, 0, stream>>>(cnts, deltas, dens, out);
}

// Round 6
// 94.856 us; speedup vs baseline: 1.4014x; 1.4014x over previous
//
#include <hip/hip_runtime.h>

// HistoLoss: B=1024, T=256, C=16, NB=64; TC=4096; x flat = [b][tc]
//
// R18 diagnostic (REPS=4): k1 compute C = (132.9-89.6)/3 = 14.4us;
// VALUBusy 80%, Occ 65%, bank-conflicts ~0, HBM ~0. VALU-busy time
// 0.8*71us = 57us over 33.6M wave-inst => ~4.1 cyc/VOP3P wave-inst:
// VOP3P (v_pk_*) issues at HALF the VOP2 rate (m07: VOP2 = 2 cyc).
// This explains R15's flat result (pk halved inst count, doubled
// cyc/inst).
//
// R19 (this round):
//  - k1 inner: back to R12-proven 3xVOP2 shared-vcc indicator (sub/
//    cmp/addc, 2cyc each) at R17 geometry: 12.58M wave-inst * 2cyc /
//    1024 SIMD = 10.2us issue; at 80% duty -> C ~12.7us (-1.7).
//  - k2: 512 blocks x 2 items/thread (u16 chunk loads) for 2x latency
//    overlap (-~1us).
// Predict total ~86 +/- 1.5us, absmax 0.0.
//
// k1: 256 thr = 16 c x 16 kq (KPT=4 bins), block = (t, 64-b chunk),
//     grid 4096. x staged as i32 fixed-point (x*4096; bit-exact:
//     |xq-qlo| window test unsigned, wrap-safe). LDS xsi[c][68]
//     (64 + 4 pad): 16-lane broadcast, 4 disjoint b128 spans/wave =
//     conflict-free. 16 x ds_read_b128; 16g x 4q x 4j x 3 VOP2 = 768
//     inst/thread. Counts <=64 -> 4 x u8 -> one u32 store.

#define T_DIM   256
#define C_DIM   16
#define NB      64
#define TC      4096
#define CHUNKS  16
#define BBLK    64
#define KPT     4
#define PITCHI  68             // xsi row pitch in i32 (64 + 4 pad)
#define QSCALE  4096.0f        // fixed-point scale (|xq| < 2^15)

__global__ __launch_bounds__(256, 8) void histo_count_kernel(
    const float* __restrict__ x,       // [1024, 4096]
    const float* __restrict__ locs,    // [4096, 64]
    const float* __restrict__ deltas,  // [4096]
    unsigned char* __restrict__ counts,// [CHUNKS][4096][64] u8
    float* __restrict__ out)           // [1] (zeroed for k2's atomics)
{
    __shared__ int xsi[C_DIM * PITCHI];          // 16 x 68 i32 = 4352 B
    const int tid   = threadIdx.x;
    const int t     = blockIdx.x & 255;
    const int chunk = blockIdx.x >> 8;           // 0..15 (64 b each)

    if (blockIdx.x == 0 && tid == 0) out[0] = 0.0f;

    // Stage x[chunk*64 .. +63][t*16 .. +15] -> i32 fixed-point (x*4096).
    if (tid < 128) {
        const int bpair = tid >> 2;              // 0..31
        const int c4    = (tid & 3) * 4;
        const int b0    = 2 * bpair;
        const float* r0 = x + (size_t)(chunk * BBLK + b0) * TC + t * C_DIM + c4;
        const float4 va = *(const float4*)r0;
        const float4 vb = *(const float4*)(r0 + TC);
        const float a[4] = {va.x, va.y, va.z, va.w};
        const float b[4] = {vb.x, vb.y, vb.z, vb.w};
#pragma unroll
        for (int k = 0; k < 4; ++k) {
            xsi[(c4 + k) * PITCHI + b0]     = __float2int_rn(a[k] * QSCALE);
            xsi[(c4 + k) * PITCHI + b0 + 1] = __float2int_rn(b[k] * QSCALE);
        }
    }

    const int kq = tid & 15;           // bins [kq*4, kq*4+4)
    const int c  = tid >> 4;           // 0..15
    const int tc = t * C_DIM + c;

    const float hf = 0.5f * deltas[tc];
    const int   qw = __float2int_rn(2.0f * hf * QSCALE);   // window width

    int qlo[KPT];                       // window low edge
    const float4 lv = *(const float4*)(locs + (size_t)tc * NB + kq * KPT);
    const float lf[4] = {lv.x, lv.y, lv.z, lv.w};
#pragma unroll
    for (int j = 0; j < KPT; ++j)
        qlo[j] = __float2int_rn((lf[j] - hf) * QSCALE);

    int acc[KPT];
#pragma unroll
    for (int j = 0; j < KPT; ++j) acc[j] = 0;

    __syncthreads();

    // 16 iters x (1 ds_read_b128 = 4 xi) x 4 bins x 4 x 3 VOP2 inst.
    const int4* xr = (const int4*)(xsi + c * PITCHI);
#pragma unroll 4
    for (int g = 0; g < 16; ++g) {
        const int4 u = xr[g];
        const int xi[4] = {u.x, u.y, u.z, u.w};
#pragma unroll
        for (int j = 0; j < KPT; ++j) {
#pragma unroll
            for (int q = 0; q < 4; ++q) {
                int tmp;
                asm("v_sub_u32 %0, %2, %3\n\t"
                    "v_cmp_lt_u32 vcc, %0, %4\n\t"
                    "v_addc_co_u32 %1, vcc, 0, %1, vcc"
                    : "=&v"(tmp), "+v"(acc[j])
                    : "v"(xi[q]), "v"(qlo[j]), "v"(qw)
                    : "vcc");
            }
        }
    }

    unsigned pack = 0;
#pragma unroll
    for (int j = 0; j < KPT; ++j)
        pack |= ((unsigned)acc[j] & 0xFFu) << (8 * j);     // <=64 each
    *(unsigned*)(counts + (size_t)chunk * (TC * NB)
                        + (size_t)tc * NB + kq * KPT) = pack;
}

__global__ __launch_bounds__(256) void histo_loss_kernel(
    const unsigned char* __restrict__ counts, // [CHUNKS][4096][64]
    const float* __restrict__ deltas,         // [4096]
    const float* __restrict__ dens,           // [4096, 64]
    float* __restrict__ out)                  // [1]
{
    const int gid = blockIdx.x * 256 + threadIdx.x;
    const int i0  = gid * 2;                  // 2 consecutive items, same tc
                                              // (i0 even => i0,i0+1 share tc)
    int cnt[2] = {0, 0};
#pragma unroll
    for (int ch = 0; ch < CHUNKS; ++ch) {
        const unsigned u =
            *(const unsigned short*)(counts + (size_t)ch * (TC * NB) + i0);
        cnt[0] += (int)(u & 0xffu);
        cnt[1] += (int)((u >> 8) & 0xffu);
    }

    const float delta = deltas[i0 >> 6];
    const float2 dv = *(const float2*)(dens + i0);
    // Reference order: (cnt/1024) exact, then / delta.
    float s = fabsf((cnt[0] * (1.0f / 1024.0f)) / delta - dv.x)
            + fabsf((cnt[1] * (1.0f / 1024.0f)) / delta - dv.y);

#pragma unroll
    for (int off = 32; off > 0; off >>= 1)
        s += __shfl_down(s, off, 64);

    __shared__ float sb[4];
    if ((threadIdx.x & 63) == 0) sb[threadIdx.x >> 6] = s;
    __syncthreads();

    if (threadIdx.x == 0)   // REG * mean over (t,c,k) = sum / 262144
        atomicAdd(out, (sb[0] + sb[1] + sb[2] + sb[3]) * (1.0f / 262144.0f));
}

extern "C" void kernel_launch(void* const* d_in, const int* in_sizes, int n_in,
                              void* d_out, int out_size, void* d_ws, size_t ws_size,
                              hipStream_t stream) {
    const float* x      = (const float*)d_in[0];  // x_fake    [1024,256,16]
    const float* locs   = (const float*)d_in[1];  // locs      [256,16,64]
    const float* deltas = (const float*)d_in[2];  // deltas    [256,16]
    const float* dens   = (const float*)d_in[3];  // densities [256,16,64]
    float* out = (float*)d_out;
    unsigned char* cnts = (unsigned char*)d_ws;   // 4 MB scratch

    histo_count_kernel<<<T_DIM * CHUNKS, 256, 0, stream>>>(x, locs, deltas, cnts, out);
    histo_loss_kernel<<<(TC * NB) / (256 * 2), 256, 0, stream>>>(cnts, deltas, dens, out);
}

// Round 7
// 90.359 us; speedup vs baseline: 1.4712x; 1.0498x over previous
//
#include <hip/hip_runtime.h>

// HistoLoss: B=1024, T=256, C=16, NB=64; TC=4096; x flat = [b][tc]
//
// R20 = CLEAN REVERT to R17 (verified 89.62us, absmax 0.0, session best).
//
// Session model (all HW-verified this session):
//  - 43.4us: harness ws re-poison (268MB fill @ 6.2TB/s) - immovable.
//  - ~20-25us: harness restores/launch gaps (unexplained residual).
//  - k1 ~17.5us: stage ~3 + compute 14.4 (R18 REPS diagnostic).
//      VALUBusy 80%, Occ 65%, bank-conflicts ~0, HBM ~0 => VALU-bound.
//      VOP3P (v_pk_*) = 4.1 cyc/wave-inst (R18 arithmetic) -- half rate
//      vs VOP2. pk path: 2 inst/indicator * 4cyc = 8 cyc/ind.
//      VOP2 sub/cmp/addc triplet: 3 inst/ind, measured 2.9-3.9 cyc/inst
//      (vcc serialization) = 9-12 cyc/ind => pk wins (R19 falsified the
//      "VOP2@2cyc" model, +5.2us).
//      R15 washout explained: pk halved inst count, doubled cyc/inst.
//  - k2 ~4-5us (R17 form proven; R19's u16/512-block variant possibly
//      regressed -- do not bundle experiments).
//
// k1: 256 thr = 16 c x 16 kq; block = (t, 64-b chunk), grid 4096.
//     Stage by 128 thr: f32 -> u16-pair fixed-point (x*4096), rows
//     b0|b0+1 packed in u32. Bit-exact predicate: (u16)(x-qlo) < qw;
//     |xq-qlo| <= ~35K < 65536-qw so 16-bit modular wrap preserves the
//     unsigned test. LDS xsp[c][36] u32 (32 pairs + 4 pad): 16-lane
//     broadcast, disjoint 4-bank spans per c (conflict-free); staging
//     writes 2-way (free).
//     Inner: 8 x ds_read_b128 x 4 pairs x 4 bins x 4 VOP3P
//     (pk_sub / pk_sub-clamp / pk_min / pk_add) = 2 inst/indicator.
// k2: 256 blocks x 4 items/thread, u32 chunk loads; sum 16 chunk u8s,
//     loss, block-reduce, one atomicAdd/block (out[0] zeroed by k1
//     block 0; stream-ordered).

#define T_DIM   256
#define C_DIM   16
#define NB      64
#define TC      4096
#define CHUNKS  16
#define BBLK    64             // b-rows per block
#define KPT     4              // bins per thread
#define PITCH   36             // xsp row pitch in u32 (32 pairs + 4 pad)
#define QSCALE  4096.0f        // fixed-point scale (|xq| < 2^15)

__global__ __launch_bounds__(256, 8) void histo_count_kernel(
    const float* __restrict__ x,       // [1024, 4096]
    const float* __restrict__ locs,    // [4096, 64]
    const float* __restrict__ deltas,  // [4096]
    unsigned char* __restrict__ counts,// [CHUNKS][4096][64] u8
    float* __restrict__ out)           // [1] (zeroed for k2's atomics)
{
    __shared__ int xsp[C_DIM * PITCH];           // 16 x 36 u32 = 2304 B
    const int tid   = threadIdx.x;
    const int t     = blockIdx.x & 255;
    const int chunk = blockIdx.x >> 8;           // 0..15 (64 b each)

    if (blockIdx.x == 0 && tid == 0) out[0] = 0.0f;

    // Stage x[chunk*64 .. +63][t*16 .. +15] -> u16-pair fixed-point.
    // 128 threads: row b0 (even) -> lo16, row b0+1 (odd) -> hi16.
    if (tid < 128) {
        const int bpair = tid >> 2;              // 0..31
        const int c4    = (tid & 3) * 4;
        const int b0    = 2 * bpair;
        const float* r0 = x + (size_t)(chunk * BBLK + b0) * TC + t * C_DIM + c4;
        const float4 va = *(const float4*)r0;
        const float4 vb = *(const float4*)(r0 + TC);
        const float a[4] = {va.x, va.y, va.z, va.w};
        const float b[4] = {vb.x, vb.y, vb.z, vb.w};
#pragma unroll
        for (int k = 0; k < 4; ++k) {
            const int pa = __float2int_rn(a[k] * QSCALE);
            const int pb = __float2int_rn(b[k] * QSCALE);
            xsp[(c4 + k) * PITCH + bpair] = (pa & 0xFFFF) | (pb << 16);
        }
    }

    const int kq = tid & 15;           // bins [kq*4, kq*4+4)
    const int c  = tid >> 4;           // 0..15
    const int tc = t * C_DIM + c;

    const float hf = 0.5f * deltas[tc];
    const int   qw = __float2int_rn(2.0f * hf * QSCALE);   // window width
    const int   w2 = (qw & 0xFFFF) | (qw << 16);           // replicated
    const int  one2 = 0x00010001;

    int lo2[KPT];                       // window low edge, replicated u16x2
    const float4 lv = *(const float4*)(locs + (size_t)tc * NB + kq * KPT);
    const float lf[4] = {lv.x, lv.y, lv.z, lv.w};
#pragma unroll
    for (int j = 0; j < KPT; ++j) {
        const int q = __float2int_rn((lf[j] - hf) * QSCALE);
        lo2[j] = (q & 0xFFFF) | (q << 16);
    }

    int acc[KPT];                       // u16x2: even-b count | odd-b count
#pragma unroll
    for (int j = 0; j < KPT; ++j) acc[j] = 0;

    __syncthreads();

    // 8 iters x (1 ds_read_b128 = 8 x's as 4 u16-pairs) x 4 pairs x
    // 4 bins x 4 VOP3P = 2 inst/indicator. 512 pk-inst/thread.
    const int4* xr = (const int4*)(xsp + c * PITCH);
#pragma unroll 4
    for (int g = 0; g < 8; ++g) {
        const int4 u = xr[g];
        const int xx[4] = {u.x, u.y, u.z, u.w};
#pragma unroll
        for (int q = 0; q < 4; ++q) {
#pragma unroll
            for (int j = 0; j < KPT; ++j) {
                int tmp;
                asm("v_pk_sub_u16 %0, %2, %3\n\t"
                    "v_pk_sub_u16 %0, %4, %0 clamp\n\t"
                    "v_pk_min_u16 %0, %0, %5\n\t"
                    "v_pk_add_u16 %1, %1, %0"
                    : "=&v"(tmp), "+v"(acc[j])
                    : "v"(xx[q]), "v"(lo2[j]), "v"(w2), "v"(one2));
            }
        }
    }

    unsigned pack = 0;
#pragma unroll
    for (int j = 0; j < KPT; ++j) {
        const unsigned s = ((unsigned)acc[j] + ((unsigned)acc[j] >> 16)) & 0xFFu;
        pack |= s << (8 * j);                              // <=64 each
    }
    *(unsigned*)(counts + (size_t)chunk * (TC * NB)
                        + (size_t)tc * NB + kq * KPT) = pack;
}

__global__ __launch_bounds__(256) void histo_loss_kernel(
    const unsigned char* __restrict__ counts, // [CHUNKS][4096][64]
    const float* __restrict__ deltas,         // [4096]
    const float* __restrict__ dens,           // [4096, 64]
    float* __restrict__ out)                  // [1]
{
    const int gid = blockIdx.x * 256 + threadIdx.x;
    const int i0  = gid * 4;                  // 4 consecutive items, same tc

    int cnt[4] = {0, 0, 0, 0};
#pragma unroll
    for (int ch = 0; ch < CHUNKS; ++ch) {
        const unsigned u = *(const unsigned*)(counts + (size_t)ch * (TC * NB) + i0);
#pragma unroll
        for (int q = 0; q < 4; ++q)
            cnt[q] += (int)((u >> (8 * q)) & 0xffu);
    }

    const float delta = deltas[i0 >> 6];
    const float4 dv = *(const float4*)(dens + i0);
    // Reference order: (cnt/1024) exact, then / delta.
    float s = fabsf((cnt[0] * (1.0f / 1024.0f)) / delta - dv.x)
            + fabsf((cnt[1] * (1.0f / 1024.0f)) / delta - dv.y)
            + fabsf((cnt[2] * (1.0f / 1024.0f)) / delta - dv.z)
            + fabsf((cnt[3] * (1.0f / 1024.0f)) / delta - dv.w);

#pragma unroll
    for (int off = 32; off > 0; off >>= 1)
        s += __shfl_down(s, off, 64);

    __shared__ float sb[4];
    if ((threadIdx.x & 63) == 0) sb[threadIdx.x >> 6] = s;
    __syncthreads();

    if (threadIdx.x == 0)   // REG * mean over (t,c,k) = sum / 262144
        atomicAdd(out, (sb[0] + sb[1] + sb[2] + sb[3]) * (1.0f / 262144.0f));
}

extern "C" void kernel_launch(void* const* d_in, const int* in_sizes, int n_in,
                              void* d_out, int out_size, void* d_ws, size_t ws_size,
                              hipStream_t stream) {
    const float* x      = (const float*)d_in[0];  // x_fake    [1024,256,16]
    const float* locs   = (const float*)d_in[1];  // locs      [256,16,64]
    const float* deltas = (const float*)d_in[2];  // deltas    [256,16]
    const float* dens   = (const float*)d_in[3];  // densities [256,16,64]
    float* out = (float*)d_out;
    unsigned char* cnts = (unsigned char*)d_ws;   // 4 MB scratch

    histo_count_kernel<<<T_DIM * CHUNKS, 256, 0, stream>>>(x, locs, deltas, cnts, out);
    histo_loss_kernel<<<(TC * NB) / (256 * 4), 256, 0, stream>>>(cnts, deltas, dens, out);
}